// Round 2
// baseline (664.632 us; speedup 1.0000x reference)
//
#include <hip/hip_runtime.h>

typedef float v16f __attribute__((ext_vector_type(16)));
typedef int v8i __attribute__((ext_vector_type(8)));
typedef int v2i __attribute__((ext_vector_type(2)));
typedef unsigned short ushort_t;
typedef unsigned char uchar_t;
typedef long long ll_t;

#define HH 768
#define WW 768
#define CH 3
#define KS 24
#define HC 745
#define WC 745
#define NP 256
#define XH 384
#define XW 384

#define NBX 24            // ceil(745/32)
#define NBY 94            // ceil(745/8)
#define NBLK (NBX*NBY)    // 2256
#define BROWS 8
#define BCOLS 32
#define NSTEP 27          // K=1728 in 64-wide slices (8 octets each)
#define NCAND 8
#define NGRID (8*576)     // XCD-banded launch (some idle)

// async global->LDS DMA; LDS dest = wave-uniform base + lane*size (global addr per-lane)
__device__ __forceinline__ void gload16(const uchar_t* g, uchar_t* l) {
    __builtin_amdgcn_global_load_lds(
        (const __attribute__((address_space(1))) unsigned int*)(const void*)g,
        (__attribute__((address_space(3))) unsigned int*)(void*)l, 16, 0, 0);
}
__device__ __forceinline__ ushort_t f2bf(float f) {
    union { __bf16 h; ushort_t u; } cv; cv.h = (__bf16)f; return cv.u;
}
__device__ __forceinline__ float bf2f(ushort_t u) {
    union { unsigned u; float f; } cv; cv.u = ((unsigned)u) << 16; return cv.f;
}
// fp32 -> OCP e4m3fn (RNE for normals; grid-round for subnormals). Screen-only precision.
__device__ __forceinline__ uchar_t f2e4m3(float f) {
    unsigned u = __float_as_uint(f);
    unsigned s = (u >> 24) & 0x80;
    float a = fabsf(f);
    if (a < 0.0078125f) {
        int q = (int)(a * 512.0f + 0.5f);
        return (uchar_t)(s | (unsigned)q);
    }
    int e = (int)((u >> 23) & 0xFF);
    unsigned m = (u >> 20) & 7;
    unsigned rest = u & 0xFFFFF;
    if (rest > 0x80000 || (rest == 0x80000 && (m & 1))) { m++; if (m == 8) { m = 0; e++; } }
    int e8 = e - 120;
    if (e8 <= 0) { int q = (int)(a * 512.0f + 0.5f); if (q > 7) q = 7; return (uchar_t)(s | q); }
    if (e8 > 15) return (uchar_t)(s | 0x7E);
    return (uchar_t)(s | ((unsigned)e8 << 3) | m);
}

// -------------------- prep kernels --------------------

__global__ void k_colsum(const float* __restrict__ y, float* __restrict__ ksum,
                         float* __restrict__ ksum2) {
    int idx = blockIdx.x * 256 + threadIdx.x;
    if (idx >= HH * WW) return;
    float a = y[idx], b = y[idx + HH * WW], c = y[idx + 2 * HH * WW];
    ksum[idx]  = a + b + c;
    ksum2[idx] = a * a + b * b + c * c;
}

__global__ void k_hsum(const float* __restrict__ ksum, const float* __restrict__ ksum2,
                       float* __restrict__ h1, float* __restrict__ h2) {
    int idx = blockIdx.x * 256 + threadIdx.x;
    if (idx >= HH * WC) return;
    int h = idx / WC, w = idx % WC;
    const float* r  = ksum  + h * WW + w;
    const float* r2 = ksum2 + h * WW + w;
    float s = 0.f, s2 = 0.f;
    #pragma unroll
    for (int j = 0; j < KS; j++) { s += r[j]; s2 += r2[j]; }
    h1[idx] = s; h2[idx] = s2;
}

// bf16 maps are ONLY used for the approximate pre-screen; k_rescore recomputes exactly.
__global__ void k_vsum(const float* __restrict__ h1, const float* __restrict__ h2,
                       ushort_t* __restrict__ s1m, ushort_t* __restrict__ ivm) {
    int idx = blockIdx.x * 256 + threadIdx.x;
    if (idx >= HC * WC) return;
    int r = idx / WC, w = idx % WC;
    float s = 0.f, s2 = 0.f;
    #pragma unroll
    for (int i = 0; i < KS; i++) { s += h1[(r + i) * WC + w]; s2 += h2[(r + i) * WC + w]; }
    float d2 = s2 - s * s * (1.0f / 576.0f);
    s1m[idx] = f2bf(s);
    ivm[idx] = f2bf(rsqrtf(fmaxf(d2, 1e-20f)));
}

__global__ void k_meanx(const float* __restrict__ x, float* __restrict__ mx) {
    int p = blockIdx.x;
    int pr = p >> 4, pc = p & 15;
    float s = 0.f;
    for (int e = threadIdx.x; e < CH * KS * KS; e += 256) {
        int c = e / (KS * KS); int rem = e % (KS * KS);
        int i = rem / KS, j = rem % KS;
        s += x[(c * XH + pr * KS + i) * XW + pc * KS + j];
    }
    __shared__ float red[256];
    red[threadIdx.x] = s; __syncthreads();
    for (int st = 128; st > 0; st >>= 1) {
        if (threadIdx.x < st) red[threadIdx.x] += red[threadIdx.x + st];
        __syncthreads();
    }
    if (threadIdx.x == 0) mx[p] = red[0] * (1.0f / 1728.0f);
}

// fp8 patch matrix, K-REORDERED j-octet-major: plane o' = (j/8)*72 + c*24 + i.
// Sum over k is order-independent, and this makes the A-side LDS-band address affine.
__global__ void k_bmat8(const float* __restrict__ x, uchar_t* __restrict__ bmk) {
    int p = blockIdx.x; int pr = p >> 4, pc = p & 15;
    for (int e = threadIdx.x; e < CH * KS * KS; e += 256) {
        int c = e / (KS * KS), rem = e % (KS * KS), i = rem / KS, j = rem % KS;
        bmk[((j >> 3) * 72 + c * 24 + i) * (NP * 8) + p * 8 + (j & 7)] =
            f2e4m3(x[(c * XH + pr * KS + i) * XW + pc * KS + j]);
    }
}

// 4 column-shifted fp8 copies: y4[S][c][r][t] = fp8(ydec[c][r][t+S]), S in 0..3, 0-pad OOB.
__global__ void k_y4(const float* __restrict__ yd, uchar_t* __restrict__ y4) {
    int idx = blockIdx.x * 256 + threadIdx.x;
    if (idx >= 4 * 3 * HH * (WW / 4)) return;
    int q = idx % (WW / 4); int rem = idx / (WW / 4);
    int r = rem % HH; rem /= HH;
    int c = rem % 3; int S = rem / 3;
    const float* src = yd + (c * HH + r) * WW;
    union { uchar_t u[4]; unsigned v; } o;
    #pragma unroll
    for (int qq = 0; qq < 4; qq++) {
        int t = q * 4 + qq + S;
        o.u[qq] = f2e4m3(t < WW ? src[t] : 0.f);
    }
    ((unsigned*)(y4 + ((size_t)(S * 3 + c) * HH + r) * WW))[q] = o.v;
}

// -------------------- main MFMA correlation kernel (MX-fp8 K=64, band-A, barrier-free) ------
// 256 thr (4 waves); XCD-banded flat grid. Tile = 256 pos x 128 pat; each wave owns
// 256 pos x 32 pat (wn = wave): 8 mfma_scale_f32_32x32x64_f8f6f4 per step share ONE B
// fragment -> B DMA traffic per FLOP cut 4x vs the 128x128 tile (was the limiter:
// MfmaUtil 34% with no saturated pipe; 3.9 GB of L2->LDS DMA).
//  * A: the tile's ENTIRE K=1728 A-data is one 3x31x56 pixel band (5.2 KB; im2col dup).
//    Loaded ONCE into LDS as 4 column-shifted copies (stride 5280 B: word-stride 1320 = 8
//    mod 32 -> each frag read covers all 32 banks exactly once, conflict-free). Band row =
//    pos_row + k_octet collapses mt+q: 11 rows (22 ds_read_b32) feed all 8 MFMAs.
//  * B: wave-PRIVATE 2 KB slices (only its 32 patches: 2 coalesced gload16, double-
//    buffered) -> no duplication, no cross-wave dependency -> ZERO barriers in the K-loop;
//    per-wave s_waitcnt vmcnt(2) is the only sync (prefetch in flight, never drained to 0).
//  * Patches are wave-exclusive -> epilogue is shfl+store, no LDS reduction.

__global__ __launch_bounds__(256, 2) void k_corr(
    const uchar_t* __restrict__ y4, const uchar_t* __restrict__ bmk,
    const ushort_t* __restrict__ s1m, const ushort_t* __restrict__ ivm,
    const float* __restrict__ mx, ushort_t* __restrict__ ps16)
{
    // ---- XCD-band mapping (heuristic blk%8 -> XCD; wrong mapping only costs speed) ----
    const int xcd = blockIdx.x & 7;
    const int idx = blockIdx.x >> 3;
    const int bstart = (NBY * xcd) >> 3;
    const int bcnt = ((NBY * (xcd + 1)) >> 3) - bstart;
    const int local_by = idx / 48;
    if (local_by >= bcnt) return;                    // idle filler block
    const int rem = idx - local_by * 48;
    const int z = rem / 24;                          // patch half
    const int bx = rem - z * 24;
    const int by = bstart + local_by;

    __shared__ __align__(16) uchar_t Aband[21120];   // 4 copies x 93 rows x 56 B (stride 5280)
    __shared__ __align__(16) uchar_t Bb[16384];      // 2 buf x 4 waves x [8 planes][32 pat][8B]

    const int tid = threadIdx.x;
    const int wave = tid >> 6, lane = tid & 63;
    const int r0 = by * BROWS, w0 = bx * BCOLS;
    const int zbase = z * 128;
    const int l31 = lane & 31, h = lane >> 5;
    const int wn = wave;                             // patch group (wave-exclusive)

    // ---- prologue: load A band (rows r0..r0+30, cols w0..w0+55) from the 4 shifted planes ----
    for (int e = tid; e < 5208; e += 256) {          // 4 copies x 93 rows x 14 dwords
        int dw = e % 14;
        int row93 = (e / 14) % 93;
        int S = e / 1302;
        int c = row93 / 31, r = row93 - c * 31;
        int gr = r0 + r; gr = gr < HH ? gr : HH - 1; // clamp feeds only masked-invalid positions
        unsigned v = *(const unsigned*)(y4 + ((size_t)(S * 3 + c) * HH + gr) * WW + w0 + dw * 4);
        *(unsigned*)(Aband + S * 5280 + row93 * 56 + dw * 4) = v;
    }

    // ---- B staging (wave-private): 8 planes x 32 pat x 8B per slice = 2 KB, 2 DMAs ----
    // lane l covers plane (l>>4) of the 4-plane group, bytes (l&15)*16
    const uchar_t* gB = bmk + (size_t)(lane >> 4) * 2048 + (size_t)(zbase + wn * 32) * 8
                      + (lane & 15) * 16;
    uchar_t* bwave = Bb + wave * 2048;
    auto stageB = [&](int s, int buf) {
        uchar_t* bd = bwave + buf * 8192;
        const uchar_t* g = gB + (size_t)s * 16384;
        gload16(g,        bd);                       // planes 0..3 of slice
        gload16(g + 8192, bd + 1024);                // planes 4..7
    };

    stageB(0, 0);

    // A frag lane base: addr = sh*5280 + (c*31 + pr_off + ibase + 4h + q)*56 + (l31 + jo*8 - sh)
    //                 = [sh*5279 + l31 + h*224] + U(s) + (mt+q)*56
    //   (pr_off = mt; j0 = jo*8 = 0 mod 4 -> shift copy sh = l31&3 is lane-constant;
    //    sh ≡ l31 mod 4 keeps the base dword-aligned)
    const uchar_t* Abase0 = Aband + (l31 & 3) * 5279 + l31 + h * 224;

    v16f acc[8];
    #pragma unroll
    for (int a = 0; a < 8; a++)
        #pragma unroll
        for (int r = 0; r < 16; r++) acc[a][r] = 0.f;

    __syncthreads();                                 // band visible to all waves (one-time)

    int U = 0, j3 = 0, c3 = 0;                       // uniform cursor: U = c*1736 + ibase*56 + jo*8
    #pragma unroll 1
    for (int s = 0; s < NSTEP; s++) {
        if (s + 1 < NSTEP) {
            stageB(s + 1, (s + 1) & 1);              // 2 new DMAs in flight
            asm volatile("s_waitcnt vmcnt(2)" ::: "memory");   // slice-s's 2 (older) landed
        } else {
            asm volatile("s_waitcnt vmcnt(0)" ::: "memory");
        }
        const uchar_t* Ap = Abase0 + U;
        const uchar_t* Bp = bwave + (s & 1) * 8192 + h * 1024 + l31 * 8;

        // 11 distinct band rows (mt+q in 0..10), lo/hi dwords each
        unsigned ad[22];
        #pragma unroll
        for (int r = 0; r < 11; r++) {
            ad[2 * r]     = *(const unsigned*)(Ap + r * 56);
            ad[2 * r + 1] = *(const unsigned*)(Ap + r * 56 + 4);
        }
        v8i bf8;
        #pragma unroll
        for (int q = 0; q < 4; q++) {                // planes 4h+q, patches wn*32+l31
            v2i b0 = *(const v2i*)(Bp + q * 256);
            bf8[2 * q] = b0.x; bf8[2 * q + 1] = b0.y;
        }
        #pragma unroll
        for (int mt = 0; mt < 8; mt++) {
            v8i af8;
            #pragma unroll
            for (int q = 0; q < 4; q++) {
                af8[2 * q]     = (int)ad[2 * (mt + q)];
                af8[2 * q + 1] = (int)ad[2 * (mt + q) + 1];
            }
            acc[mt] = __builtin_amdgcn_mfma_scale_f32_32x32x64_f8f6f4(
                af8, bf8, acc[mt], 0 /*A=fp8*/, 0 /*B=fp8*/, 0, 0x7F7F7F7F, 0, 0x7F7F7F7F);
        }

        if (++j3 < 3) U += 448;                      // ibase += 8
        else { j3 = 0; if (++c3 < 3) U += 840;       // c += 1, ibase -> 0
               else { c3 = 0; U -= 4360; } }         // jo += 1, c -> 0
    }

    // epilogue: approx score + per-patch max over this block's 256 positions
    float mxp = mx[zbase + wn * 32 + l31];
    float best = -1e30f;
    #pragma unroll
    for (int mt = 0; mt < 8; mt++) {
        int rg = r0 + mt;
        #pragma unroll
        for (int r = 0; r < 16; r++) {
            int row32 = (r & 3) + 8 * (r >> 2) + 4 * h;   // 32x32 C/D row (m74/m101)
            int wg = w0 + row32;
            bool valid = (rg < HC) && (wg < WC);
            int pos = rg * WC + wg;
            float S1 = valid ? bf2f(s1m[pos]) : 0.f;
            float iv = valid ? bf2f(ivm[pos]) : 0.f;
            float sc = valid ? (acc[mt][r] - mxp * S1) * iv : -1e30f;
            best = fmaxf(best, sc);
        }
    }
    best = fmaxf(best, __shfl_xor(best, 32));        // reduce over h
    if (h == 0)
        ps16[(by * NBX + bx) * NP + zbase + wn * 32 + l31] = f2bf(best);
}

// -------------------- per-patch top-8 blocks --------------------

__global__ void k_select(const ushort_t* __restrict__ ps16, int* __restrict__ cand) {
    int p = blockIdx.x, tid = threadIdx.x;
    __shared__ float ls[NBLK];
    __shared__ float rs[256];
    __shared__ int   ri[256];
    for (int e = tid; e < NBLK; e += 256) ls[e] = bf2f(ps16[e * NP + p]);
    __syncthreads();
    for (int round = 0; round < NCAND; round++) {
        float bs = -1e38f; int bi = 0;
        for (int e = tid; e < NBLK; e += 256) if (ls[e] > bs) { bs = ls[e]; bi = e; }
        rs[tid] = bs; ri[tid] = bi; __syncthreads();
        for (int st = 128; st > 0; st >>= 1) {
            if (tid < st && rs[tid + st] > rs[tid]) { rs[tid] = rs[tid + st]; ri[tid] = ri[tid + st]; }
            __syncthreads();
        }
        int win = ri[0];
        if (tid == 0) cand[p * NCAND + round] = win;
        if (tid == (win & 255)) ls[win] = -1e38f;
        __syncthreads();
    }
}

// -------------------- exact fp32 rescore (recomputes window sums) + gather --------------------

__global__ void k_rescore(const int* __restrict__ cand, const float* __restrict__ xdec,
                          const float* __restrict__ ydec, const float* __restrict__ mx,
                          const float* __restrict__ yfull, float* __restrict__ out) {
    int p = blockIdx.x, tid = threadIdx.x;
    int pr = p >> 4, pc = p & 15;
    float mxp = mx[p];
    float best = -1e30f; int bpos = 0x7FFFFFFF;
    #pragma unroll 1
    for (int cd = 0; cd < NCAND; cd++) {
        int blk = cand[p * NCAND + cd];
        int r0 = (blk / NBX) * BROWS, w0 = (blk % NBX) * BCOLS;
        int rg = r0 + (tid >> 5), wg = w0 + (tid & 31);
        if (rg < HC && wg < WC) {
            float sxy = 0.f, sy = 0.f, sy2 = 0.f;
            for (int c = 0; c < CH; c++) {
                #pragma unroll 1
                for (int i = 0; i < KS; i++) {
                    const float* yr = ydec + (c * HH + rg + i) * WW + wg;
                    const float* xr = xdec + (c * XH + pr * KS + i) * XW + pc * KS;
                    #pragma unroll
                    for (int j = 0; j < KS; j++) {
                        float yv = yr[j];
                        sxy = fmaf(yv, xr[j], sxy);
                        sy += yv;
                        sy2 = fmaf(yv, yv, sy2);
                    }
                }
            }
            float d2 = sy2 - sy * sy * (1.0f / 576.0f);
            int pos = rg * WC + wg;
            float sc = (sxy - mxp * sy) * rsqrtf(fmaxf(d2, 1e-20f));
            if (sc > best || (sc == best && pos < bpos)) { best = sc; bpos = pos; }
        }
    }
    __shared__ float rs[256];
    __shared__ int   ri[256];
    rs[tid] = best; ri[tid] = bpos; __syncthreads();
    for (int st = 128; st > 0; st >>= 1) {
        if (tid < st) {
            if (rs[tid + st] > rs[tid] || (rs[tid + st] == rs[tid] && ri[tid + st] < ri[tid])) {
                rs[tid] = rs[tid + st]; ri[tid] = ri[tid + st];
            }
        }
        __syncthreads();
    }
    int bestpos = ri[0];
    int row = bestpos / WC, col = bestpos % WC;
    for (int e = tid; e < CH * KS * KS; e += 256) {
        int c = e / (KS * KS), rem = e % (KS * KS), i = rem / KS, j = rem % KS;
        out[p * CH * KS * KS + e] = yfull[(c * HH + row + i) * WW + col + j];
    }
}

// -------------------- launch --------------------
// ws footprint: writes end < 12.1 MB (y4 ends at 12,047,488 B; +<=20 B transient OOB reads)
// — safely under the >=13.7 MB proven previously.

extern "C" void kernel_launch(void* const* d_in, const int* in_sizes, int n_in,
                              void* d_out, int out_size, void* d_ws, size_t ws_size,
                              hipStream_t stream) {
    const float* xdec = (const float*)d_in[0];   // (1,3,384,384)
    const float* ydec = (const float*)d_in[1];   // (1,3,768,768)
    const float* y    = (const float*)d_in[2];   // (1,3,768,768)
    float* out = (float*)d_out;                  // (256,3,24,24)

    float* ws = (float*)d_ws;
    ushort_t* s1m16 = (ushort_t*)(ws + 0);         // 555025 u16
    ushort_t* ivm16 = (ushort_t*)(ws + 277520);    // 555025 u16
    float*    mx    = ws + 555040;                 // 256
    uchar_t*  Bmk   = (uchar_t*)(ws + 555296);     // 442368 B, k-major reordered (16B-aligned)
    int*      cand  = (int*)(ws + 665888);         // 2048
    ushort_t* ps16  = (ushort_t*)(ws + 667936);    // 2256*256 u16 [blk][pat] (1.16 MB, fits old slot)
    uchar_t*  y4    = (uchar_t*)(ws + 1242400);    // 7,077,888 B (16B-aligned)
    // box-sum temps alias ps16+y4 region (dead before k_y4/k_corr):
    float* ksum  = ws + 667936;                    // 589824
    float* ksum2 = ws + 1257760;                   // 589824
    float* h1    = ws + 1847584;                   // 572160
    float* h2    = ws + 2419744;                   // 572160 (end 2,991,904 < 3,011,872)

    k_colsum<<<(HH * WW + 255) / 256, 256, 0, stream>>>(ydec, ksum, ksum2);
    k_hsum<<<(HH * WC + 255) / 256, 256, 0, stream>>>(ksum, ksum2, h1, h2);
    k_vsum<<<(HC * WC + 255) / 256, 256, 0, stream>>>(h1, h2, s1m16, ivm16);
    k_meanx<<<NP, 256, 0, stream>>>(xdec, mx);
    k_bmat8<<<NP, 256, 0, stream>>>(xdec, Bmk);
    k_y4<<<(4 * 3 * HH * (WW / 4) + 255) / 256, 256, 0, stream>>>(ydec, y4);

    k_corr<<<NGRID, 256, 0, stream>>>(y4, Bmk, s1m16, ivm16, mx, ps16);
    k_select<<<NP, 256, 0, stream>>>(ps16, cand);
    k_rescore<<<NP, 256, 0, stream>>>(cand, xdec, ydec, mx, y, out);
}

// Round 4
// 563.821 us; speedup vs baseline: 1.1788x; 1.1788x over previous
//
#include <hip/hip_runtime.h>

typedef float v16f __attribute__((ext_vector_type(16)));
typedef int v8i __attribute__((ext_vector_type(8)));
typedef int v4i __attribute__((ext_vector_type(4)));
typedef int v2i __attribute__((ext_vector_type(2)));
typedef unsigned short ushort_t;
typedef unsigned char uchar_t;
typedef long long ll_t;

#define HH 768
#define WW 768
#define CH 3
#define KS 24
#define HC 745
#define WC 745
#define NP 256
#define XH 384
#define XW 384

#define NBX 24            // ceil(745/32)
#define NBY 94            // ceil(745/8)
#define NBLK (NBX*NBY)    // 2256
#define BROWS 8
#define BCOLS 32
#define NSTEP 27          // K=1728 in 64-wide slices (8 octets each)
#define NCAND 8
#define NGRID (8*576)     // XCD-banded launch (some idle)

// async global->LDS DMA; LDS dest = wave-uniform base + lane*size (global addr per-lane)
__device__ __forceinline__ void gload16(const uchar_t* g, uchar_t* l) {
    __builtin_amdgcn_global_load_lds(
        (const __attribute__((address_space(1))) unsigned int*)(const void*)g,
        (__attribute__((address_space(3))) unsigned int*)(void*)l, 16, 0, 0);
}
__device__ __forceinline__ ushort_t f2bf(float f) {
    union { __bf16 h; ushort_t u; } cv; cv.h = (__bf16)f; return cv.u;
}
__device__ __forceinline__ float bf2f(ushort_t u) {
    union { unsigned u; float f; } cv; cv.u = ((unsigned)u) << 16; return cv.f;
}
// fp32 -> OCP e4m3fn (RNE for normals; grid-round for subnormals). Screen-only precision.
__device__ __forceinline__ uchar_t f2e4m3(float f) {
    unsigned u = __float_as_uint(f);
    unsigned s = (u >> 24) & 0x80;
    float a = fabsf(f);
    if (a < 0.0078125f) {
        int q = (int)(a * 512.0f + 0.5f);
        return (uchar_t)(s | (unsigned)q);
    }
    int e = (int)((u >> 23) & 0xFF);
    unsigned m = (u >> 20) & 7;
    unsigned rest = u & 0xFFFFF;
    if (rest > 0x80000 || (rest == 0x80000 && (m & 1))) { m++; if (m == 8) { m = 0; e++; } }
    int e8 = e - 120;
    if (e8 <= 0) { int q = (int)(a * 512.0f + 0.5f); if (q > 7) q = 7; return (uchar_t)(s | q); }
    if (e8 > 15) return (uchar_t)(s | 0x7E);
    return (uchar_t)(s | ((unsigned)e8 << 3) | m);
}

// -------------------- prep kernels --------------------

__global__ void k_colsum(const float* __restrict__ y, float* __restrict__ ksum,
                         float* __restrict__ ksum2) {
    int idx = blockIdx.x * 256 + threadIdx.x;
    if (idx >= HH * WW) return;
    float a = y[idx], b = y[idx + HH * WW], c = y[idx + 2 * HH * WW];
    ksum[idx]  = a + b + c;
    ksum2[idx] = a * a + b * b + c * c;
}

__global__ void k_hsum(const float* __restrict__ ksum, const float* __restrict__ ksum2,
                       float* __restrict__ h1, float* __restrict__ h2) {
    int idx = blockIdx.x * 256 + threadIdx.x;
    if (idx >= HH * WC) return;
    int h = idx / WC, w = idx % WC;
    const float* r  = ksum  + h * WW + w;
    const float* r2 = ksum2 + h * WW + w;
    float s = 0.f, s2 = 0.f;
    #pragma unroll
    for (int j = 0; j < KS; j++) { s += r[j]; s2 += r2[j]; }
    h1[idx] = s; h2[idx] = s2;
}

// bf16 maps are ONLY used for the approximate pre-screen; k_rescore recomputes exactly.
__global__ void k_vsum(const float* __restrict__ h1, const float* __restrict__ h2,
                       ushort_t* __restrict__ s1m, ushort_t* __restrict__ ivm) {
    int idx = blockIdx.x * 256 + threadIdx.x;
    if (idx >= HC * WC) return;
    int r = idx / WC, w = idx % WC;
    float s = 0.f, s2 = 0.f;
    #pragma unroll
    for (int i = 0; i < KS; i++) { s += h1[(r + i) * WC + w]; s2 += h2[(r + i) * WC + w]; }
    float d2 = s2 - s * s * (1.0f / 576.0f);
    s1m[idx] = f2bf(s);
    ivm[idx] = f2bf(rsqrtf(fmaxf(d2, 1e-20f)));
}

__global__ void k_meanx(const float* __restrict__ x, float* __restrict__ mx) {
    int p = blockIdx.x;
    int pr = p >> 4, pc = p & 15;
    float s = 0.f;
    for (int e = threadIdx.x; e < CH * KS * KS; e += 256) {
        int c = e / (KS * KS); int rem = e % (KS * KS);
        int i = rem / KS, j = rem % KS;
        s += x[(c * XH + pr * KS + i) * XW + pc * KS + j];
    }
    __shared__ float red[256];
    red[threadIdx.x] = s; __syncthreads();
    for (int st = 128; st > 0; st >>= 1) {
        if (threadIdx.x < st) red[threadIdx.x] += red[threadIdx.x + st];
        __syncthreads();
    }
    if (threadIdx.x == 0) mx[p] = red[0] * (1.0f / 1728.0f);
}

// fp8 patch matrix, K-REORDERED and DMA-interleaved:
//   k-plane o' = (j/8)*72 + c*24 + i  (o' = 0..215), slice s = o'>>3, w = o'&7,
//   h = w>>2, q = w&3. Layout: [s][h][q>>1][pat][ (q&1)*8 + (j&7) ]  (16B per pat per qpair)
// -> one gload16 per h-group delivers LDS [h][qp][pat][16] with a LINEAR lane->dest map,
//    and each lane's 32 B of B (k=32h..32h+31) is CONTIGUOUS -> 2x ds_read_b128.
__global__ void k_bmat8(const float* __restrict__ x, uchar_t* __restrict__ bmk) {
    int p = blockIdx.x; int pr = p >> 4, pc = p & 15;
    for (int e = threadIdx.x; e < CH * KS * KS; e += 256) {
        int c = e / (KS * KS), rem = e % (KS * KS), i = rem / KS, j = rem % KS;
        int o = (j >> 3) * 72 + c * 24 + i;          // k-plane 0..215
        int s = o >> 3, w = o & 7;
        int hh = w >> 2, q = w & 3;
        bmk[(((size_t)(s * 2 + hh) * 2 + (q >> 1)) * 256 + p) * 16 + (q & 1) * 8 + (j & 7)] =
            f2e4m3(x[(c * XH + pr * KS + i) * XW + pc * KS + j]);
    }
}

// 4 column-shifted fp8 copies: y4[S][c][r][t] = fp8(ydec[c][r][t+S]), S in 0..3, 0-pad OOB.
// (8 LDS shift copies are built from these: copy sh reads plane sh&3 at byte offset sh&4.)
__global__ void k_y4(const float* __restrict__ yd, uchar_t* __restrict__ y4) {
    int idx = blockIdx.x * 256 + threadIdx.x;
    if (idx >= 4 * 3 * HH * (WW / 4)) return;
    int q = idx % (WW / 4); int rem = idx / (WW / 4);
    int r = rem % HH; rem /= HH;
    int c = rem % 3; int S = rem / 3;
    const float* src = yd + (c * HH + r) * WW;
    union { uchar_t u[4]; unsigned v; } o;
    #pragma unroll
    for (int qq = 0; qq < 4; qq++) {
        int t = q * 4 + qq + S;
        o.u[qq] = f2e4m3(t < WW ? src[t] : 0.f);
    }
    ((unsigned*)(y4 + ((size_t)(S * 3 + c) * HH + r) * WW))[q] = o.v;
}

// -------------------- main MFMA correlation kernel (MX-fp8 K=64, band-A, barrier-free) ------
// 256 thr (4 waves); XCD-banded flat grid. Tile = 256 pos x 128 pat; each wave owns
// 256 pos x 32 pat: 8 mfma_scale_f32_32x32x64_f8f6f4 per step share ONE B fragment.
// R2 post-mortem: limiter = LDS *instruction issue* (26 narrow reads/step ~ 85% of the
// per-CU round). This version cuts to 13 wide reads/step:
//  * A: 8 column-shift copies (sh = l31&7, stride 5280). Byte addr = sh*5279 + l31 + ...
//    == 0 mod 8 -> 11 x ds_read_b64 (was 22 x b32). Bank proof: word = 1320*sh + 2t + u;
//    1320 mod 32 = 8 -> w/2 mod 16 = 4*sh + t hits each residue exactly twice -> every
//    bank exactly 2x per half-wave (the wave64 free minimum).
//  * B: reordered Bmk + [h][qp][pat][16] LDS layout -> 2 x ds_read_b128 (was 4 x b64),
//    word = 4*l31: each bank exactly 4x (minimum for 1 KB). Zero-mov v8i assembly.
//  * ZERO barriers in the K-loop; per-wave s_waitcnt vmcnt(2) only (prefetch in flight).

__global__ __launch_bounds__(256, 2) void k_corr(
    const uchar_t* __restrict__ y4, const uchar_t* __restrict__ bmk,
    const ushort_t* __restrict__ s1m, const ushort_t* __restrict__ ivm,
    const float* __restrict__ mx, ushort_t* __restrict__ ps16)
{
    // ---- XCD-band mapping (heuristic blk%8 -> XCD; wrong mapping only costs speed) ----
    const int xcd = blockIdx.x & 7;
    const int idx = blockIdx.x >> 3;
    const int bstart = (NBY * xcd) >> 3;
    const int bcnt = ((NBY * (xcd + 1)) >> 3) - bstart;
    const int local_by = idx / 48;
    if (local_by >= bcnt) return;                    // idle filler block
    const int rem = idx - local_by * 48;
    const int z = rem / 24;                          // patch half
    const int bx = rem - z * 24;
    const int by = bstart + local_by;

    __shared__ __align__(16) uchar_t Aband[42240];   // 8 shift copies x 93 rows x 56 B (stride 5280)
    __shared__ __align__(16) uchar_t Bb[16384];      // 2 buf x 4 waves x [2 h][2 qp][32 pat][16B]

    const int tid = threadIdx.x;
    const int wave = tid >> 6, lane = tid & 63;
    const int r0 = by * BROWS, w0 = bx * BCOLS;
    const int zbase = z * 128;
    const int l31 = lane & 31, h = lane >> 5;
    const int wn = wave;                             // patch group (wave-exclusive)

    // ---- prologue: build 8 shift copies (rows r0..r0+30, cols 0..47 needed) ----
    // copy sh col c holds pixel w0+c+sh = global plane (sh&3) at col w0 + (sh&4) + c.
    for (int e = tid; e < 8928; e += 256) {          // 8 copies x 93 rows x 12 dwords
        int dw = e % 12;
        int row93 = (e / 12) % 93;
        int S = e / 1116;                            // shift copy 0..7
        int c = row93 / 31, r = row93 - c * 31;
        int gr = r0 + r; gr = gr < HH ? gr : HH - 1; // clamp feeds only masked-invalid positions
        unsigned v = *(const unsigned*)(y4 + ((size_t)((S & 3) * 3 + c) * HH + gr) * WW
                                        + w0 + (S & 4) + dw * 4);
        *(unsigned*)(Aband + S * 5280 + row93 * 56 + dw * 4) = v;
    }

    // ---- B staging (wave-private): 2 KB/slice = 2 DMAs; per-lane global scatter ----
    // DMA d(=h): lane l -> LDS [h=d][qp=l>>5][pat=l&31][16] (linear lane*16), source below.
    const uchar_t* gB = bmk + (size_t)(lane >> 5) * 4096
                      + (size_t)(zbase + wn * 32 + (lane & 31)) * 16;
    uchar_t* bwave = Bb + wave * 2048;
    auto stageB = [&](int s, int buf) {
        uchar_t* bd = bwave + buf * 8192;
        const uchar_t* g = gB + (size_t)s * 16384;
        gload16(g,        bd);                       // h = 0
        gload16(g + 8192, bd + 1024);                // h = 1
    };

    stageB(0, 0);

    // A frag lane base: addr = sh*5280 + (c*31 + ibase + 4h + q + mt)*56 + (l31 - sh + 8jo)
    //                 = [sh*5279 + l31 + h*224] + U(s) + (mt+q)*56,  sh = l31&7
    //   (l31 - sh = 8*(l31>>3) -> every read 8B-aligned -> ds_read_b64)
    const uchar_t* Abase0 = Aband + (l31 & 7) * 5279 + l31 + h * 224;

    v16f acc[8];
    #pragma unroll
    for (int a = 0; a < 8; a++)
        #pragma unroll
        for (int r = 0; r < 16; r++) acc[a][r] = 0.f;

    __syncthreads();                                 // band visible to all waves (one-time)

    int U = 0, j3 = 0, c3 = 0;                       // uniform cursor: U = c*1736 + ibase*56 + jo*8
    #pragma unroll 1
    for (int s = 0; s < NSTEP; s++) {
        if (s + 1 < NSTEP) {
            stageB(s + 1, (s + 1) & 1);              // 2 new DMAs in flight
            asm volatile("s_waitcnt vmcnt(2)" ::: "memory");   // slice-s's 2 (older) landed
        } else {
            asm volatile("s_waitcnt vmcnt(0)" ::: "memory");
        }
        const uchar_t* Ap = Abase0 + U;
        const uchar_t* Bp = bwave + (s & 1) * 8192 + h * 1024 + l31 * 16;

        // 11 distinct band rows (mt+q in 0..10), one b64 each
        v2i ad[11];
        #pragma unroll
        for (int r = 0; r < 11; r++)
            ad[r] = *(const v2i*)(Ap + r * 56);

        v4i b0 = *(const v4i*)(Bp);                  // qp=0: k bytes 0..15 of this h-half
        v4i b1 = *(const v4i*)(Bp + 512);            // qp=1: k bytes 16..31
        v8i bf8;
        bf8[0] = b0.x; bf8[1] = b0.y; bf8[2] = b0.z; bf8[3] = b0.w;
        bf8[4] = b1.x; bf8[5] = b1.y; bf8[6] = b1.z; bf8[7] = b1.w;

        #pragma unroll
        for (int mt = 0; mt < 8; mt++) {
            v8i af8;
            #pragma unroll
            for (int q = 0; q < 4; q++) {
                af8[2 * q]     = ad[mt + q].x;
                af8[2 * q + 1] = ad[mt + q].y;
            }
            acc[mt] = __builtin_amdgcn_mfma_scale_f32_32x32x64_f8f6f4(
                af8, bf8, acc[mt], 0 /*A=fp8*/, 0 /*B=fp8*/, 0, 0x7F7F7F7F, 0, 0x7F7F7F7F);
        }

        if (++j3 < 3) U += 448;                      // ibase += 8
        else { j3 = 0; if (++c3 < 3) U += 840;       // c += 1, ibase -> 0
               else { c3 = 0; U -= 4360; } }         // jo += 1, c -> 0
    }

    // epilogue: approx score + per-patch max over this block's 256 positions
    float mxp = mx[zbase + wn * 32 + l31];
    float best = -1e30f;
    #pragma unroll
    for (int mt = 0; mt < 8; mt++) {
        int rg = r0 + mt;
        #pragma unroll
        for (int r = 0; r < 16; r++) {
            int row32 = (r & 3) + 8 * (r >> 2) + 4 * h;   // 32x32 C/D row (m74/m101)
            int wg = w0 + row32;
            bool valid = (rg < HC) && (wg < WC);
            int pos = rg * WC + wg;
            float S1 = valid ? bf2f(s1m[pos]) : 0.f;
            float iv = valid ? bf2f(ivm[pos]) : 0.f;
            float sc = valid ? (acc[mt][r] - mxp * S1) * iv : -1e30f;
            best = fmaxf(best, sc);
        }
    }
    best = fmaxf(best, __shfl_xor(best, 32));        // reduce over h
    if (h == 0)
        ps16[(by * NBX + bx) * NP + zbase + wn * 32 + l31] = f2bf(best);
}

// -------------------- per-patch top-8 blocks --------------------

__global__ void k_select(const ushort_t* __restrict__ ps16, int* __restrict__ cand) {
    int p = blockIdx.x, tid = threadIdx.x;
    __shared__ float ls[NBLK];
    __shared__ float rs[256];
    __shared__ int   ri[256];
    for (int e = tid; e < NBLK; e += 256) ls[e] = bf2f(ps16[e * NP + p]);
    __syncthreads();
    for (int round = 0; round < NCAND; round++) {
        float bs = -1e38f; int bi = 0;
        for (int e = tid; e < NBLK; e += 256) if (ls[e] > bs) { bs = ls[e]; bi = e; }
        rs[tid] = bs; ri[tid] = bi; __syncthreads();
        for (int st = 128; st > 0; st >>= 1) {
            if (tid < st && rs[tid + st] > rs[tid]) { rs[tid] = rs[tid + st]; ri[tid] = ri[tid + st]; }
            __syncthreads();
        }
        int win = ri[0];
        if (tid == 0) cand[p * NCAND + round] = win;
        if (tid == (win & 255)) ls[win] = -1e38f;
        __syncthreads();
    }
}

// -------------------- exact fp32 rescore (recomputes window sums) + gather --------------------
// 512 threads: candidate pair split across tid>>8 -> 4 window-loops per thread (same
// 8-candidate x 256-position coverage as before; identical selection semantics).

__global__ void k_rescore(const int* __restrict__ cand, const float* __restrict__ xdec,
                          const float* __restrict__ ydec, const float* __restrict__ mx,
                          const float* __restrict__ yfull, float* __restrict__ out) {
    int p = blockIdx.x, tid = threadIdx.x;
    int pr = p >> 4, pc = p & 15;
    float mxp = mx[p];
    float best = -1e30f; int bpos = 0x7FFFFFFF;
    #pragma unroll 1
    for (int cdp = 0; cdp < 4; cdp++) {
        int cd = cdp * 2 + (tid >> 8);
        int blk = cand[p * NCAND + cd];
        int r0 = (blk / NBX) * BROWS, w0 = (blk % NBX) * BCOLS;
        int pi = tid & 255;
        int rg = r0 + (pi >> 5), wg = w0 + (pi & 31);
        if (rg < HC && wg < WC) {
            float sxy = 0.f, sy = 0.f, sy2 = 0.f;
            for (int c = 0; c < CH; c++) {
                #pragma unroll 1
                for (int i = 0; i < KS; i++) {
                    const float* yr = ydec + (c * HH + rg + i) * WW + wg;
                    const float* xr = xdec + (c * XH + pr * KS + i) * XW + pc * KS;
                    #pragma unroll
                    for (int j = 0; j < KS; j++) {
                        float yv = yr[j];
                        sxy = fmaf(yv, xr[j], sxy);
                        sy += yv;
                        sy2 = fmaf(yv, yv, sy2);
                    }
                }
            }
            float d2 = sy2 - sy * sy * (1.0f / 576.0f);
            int pos = rg * WC + wg;
            float sc = (sxy - mxp * sy) * rsqrtf(fmaxf(d2, 1e-20f));
            if (sc > best || (sc == best && pos < bpos)) { best = sc; bpos = pos; }
        }
    }
    __shared__ float rs[512];
    __shared__ int   ri[512];
    rs[tid] = best; ri[tid] = bpos; __syncthreads();
    for (int st = 256; st > 0; st >>= 1) {
        if (tid < st) {
            if (rs[tid + st] > rs[tid] || (rs[tid + st] == rs[tid] && ri[tid + st] < ri[tid])) {
                rs[tid] = rs[tid + st]; ri[tid] = ri[tid + st];
            }
        }
        __syncthreads();
    }
    int bestpos = ri[0];
    int row = bestpos / WC, col = bestpos % WC;
    for (int e = tid; e < CH * KS * KS; e += 512) {
        int c = e / (KS * KS), rem = e % (KS * KS), i = rem / KS, j = rem % KS;
        out[p * CH * KS * KS + e] = yfull[(c * HH + row + i) * WW + col + j];
    }
}

// -------------------- launch --------------------
// ws footprint: writes end < 12.1 MB (y4 ends at 12,047,488 B; + tiny transient OOB reads)
// — safely under the >=13.7 MB proven previously.

extern "C" void kernel_launch(void* const* d_in, const int* in_sizes, int n_in,
                              void* d_out, int out_size, void* d_ws, size_t ws_size,
                              hipStream_t stream) {
    const float* xdec = (const float*)d_in[0];   // (1,3,384,384)
    const float* ydec = (const float*)d_in[1];   // (1,3,768,768)
    const float* y    = (const float*)d_in[2];   // (1,3,768,768)
    float* out = (float*)d_out;                  // (256,3,24,24)

    float* ws = (float*)d_ws;
    ushort_t* s1m16 = (ushort_t*)(ws + 0);         // 555025 u16
    ushort_t* ivm16 = (ushort_t*)(ws + 277520);    // 555025 u16
    float*    mx    = ws + 555040;                 // 256
    uchar_t*  Bmk   = (uchar_t*)(ws + 555296);     // 442368 B, k-major+DMA-interleaved (16B-aligned)
    int*      cand  = (int*)(ws + 665888);         // 2048
    ushort_t* ps16  = (ushort_t*)(ws + 667936);    // 2256*256 u16 [blk][pat] (1.16 MB)
    uchar_t*  y4    = (uchar_t*)(ws + 1242400);    // 7,077,888 B (16B-aligned)
    // box-sum temps alias ps16+y4 region (dead before k_y4/k_corr):
    float* ksum  = ws + 667936;                    // 589824
    float* ksum2 = ws + 1257760;                   // 589824
    float* h1    = ws + 1847584;                   // 572160
    float* h2    = ws + 2419744;                   // 572160 (end 2,991,904 < 3,011,872)

    k_colsum<<<(HH * WW + 255) / 256, 256, 0, stream>>>(ydec, ksum, ksum2);
    k_hsum<<<(HH * WC + 255) / 256, 256, 0, stream>>>(ksum, ksum2, h1, h2);
    k_vsum<<<(HC * WC + 255) / 256, 256, 0, stream>>>(h1, h2, s1m16, ivm16);
    k_meanx<<<NP, 256, 0, stream>>>(xdec, mx);
    k_bmat8<<<NP, 256, 0, stream>>>(xdec, Bmk);
    k_y4<<<(4 * 3 * HH * (WW / 4) + 255) / 256, 256, 0, stream>>>(ydec, y4);

    k_corr<<<NGRID, 256, 0, stream>>>(y4, Bmk, s1m16, ivm16, mx, ps16);
    k_select<<<NP, 256, 0, stream>>>(ps16, cand);
    k_rescore<<<NP, 512, 0, stream>>>(cand, xdec, ydec, mx, y, out);
}

// Round 5
// 510.007 us; speedup vs baseline: 1.3032x; 1.1055x over previous
//
#include <hip/hip_runtime.h>

typedef float v16f __attribute__((ext_vector_type(16)));
typedef int v8i __attribute__((ext_vector_type(8)));
typedef int v2i __attribute__((ext_vector_type(2)));
typedef unsigned short ushort_t;
typedef unsigned char uchar_t;
typedef long long ll_t;

#define HH 768
#define WW 768
#define CH 3
#define KS 24
#define HC 745
#define WC 745
#define NP 256
#define XH 384
#define XW 384

#define NBX 24            // ceil(745/32)
#define NBY 187           // ceil(745/4)
#define NBLK (NBX*NBY)    // 4488
#define BROWS 4
#define BCOLS 32
#define NSTEP 27          // K=1728 in 64-wide slices (8 octets each)
#define NCAND 8
#define NGRID (8*1152)    // XCD-banded launch (some idle)

// async global->LDS DMA; LDS dest = wave-uniform base + lane*size (global addr per-lane)
__device__ __forceinline__ void gload16(const uchar_t* g, uchar_t* l) {
    __builtin_amdgcn_global_load_lds(
        (const __attribute__((address_space(1))) unsigned int*)(const void*)g,
        (__attribute__((address_space(3))) unsigned int*)(void*)l, 16, 0, 0);
}
__device__ __forceinline__ ushort_t f2bf(float f) {
    union { __bf16 h; ushort_t u; } cv; cv.h = (__bf16)f; return cv.u;
}
__device__ __forceinline__ float bf2f(ushort_t u) {
    union { unsigned u; float f; } cv; cv.u = ((unsigned)u) << 16; return cv.f;
}
// fp32 -> OCP e4m3fn (RNE for normals; grid-round for subnormals). Screen-only precision.
__device__ __forceinline__ uchar_t f2e4m3(float f) {
    unsigned u = __float_as_uint(f);
    unsigned s = (u >> 24) & 0x80;
    float a = fabsf(f);
    if (a < 0.0078125f) {
        int q = (int)(a * 512.0f + 0.5f);
        return (uchar_t)(s | (unsigned)q);
    }
    int e = (int)((u >> 23) & 0xFF);
    unsigned m = (u >> 20) & 7;
    unsigned rest = u & 0xFFFFF;
    if (rest > 0x80000 || (rest == 0x80000 && (m & 1))) { m++; if (m == 8) { m = 0; e++; } }
    int e8 = e - 120;
    if (e8 <= 0) { int q = (int)(a * 512.0f + 0.5f); if (q > 7) q = 7; return (uchar_t)(s | q); }
    if (e8 > 15) return (uchar_t)(s | 0x7E);
    return (uchar_t)(s | ((unsigned)e8 << 3) | m);
}

// -------------------- prep kernels --------------------

__global__ void k_colsum(const float* __restrict__ y, float* __restrict__ ksum,
                         float* __restrict__ ksum2) {
    int idx = blockIdx.x * 256 + threadIdx.x;
    if (idx >= HH * WW) return;
    float a = y[idx], b = y[idx + HH * WW], c = y[idx + 2 * HH * WW];
    ksum[idx]  = a + b + c;
    ksum2[idx] = a * a + b * b + c * c;
}

__global__ void k_hsum(const float* __restrict__ ksum, const float* __restrict__ ksum2,
                       float* __restrict__ h1, float* __restrict__ h2) {
    int idx = blockIdx.x * 256 + threadIdx.x;
    if (idx >= HH * WC) return;
    int h = idx / WC, w = idx % WC;
    const float* r  = ksum  + h * WW + w;
    const float* r2 = ksum2 + h * WW + w;
    float s = 0.f, s2 = 0.f;
    #pragma unroll
    for (int j = 0; j < KS; j++) { s += r[j]; s2 += r2[j]; }
    h1[idx] = s; h2[idx] = s2;
}

// bf16 maps are ONLY used for the approximate pre-screen; k_rescore recomputes exactly.
__global__ void k_vsum(const float* __restrict__ h1, const float* __restrict__ h2,
                       ushort_t* __restrict__ s1m, ushort_t* __restrict__ ivm) {
    int idx = blockIdx.x * 256 + threadIdx.x;
    if (idx >= HC * WC) return;
    int r = idx / WC, w = idx % WC;
    float s = 0.f, s2 = 0.f;
    #pragma unroll
    for (int i = 0; i < KS; i++) { s += h1[(r + i) * WC + w]; s2 += h2[(r + i) * WC + w]; }
    float d2 = s2 - s * s * (1.0f / 576.0f);
    s1m[idx] = f2bf(s);
    ivm[idx] = f2bf(rsqrtf(fmaxf(d2, 1e-20f)));
}

__global__ void k_meanx(const float* __restrict__ x, float* __restrict__ mx) {
    int p = blockIdx.x;
    int pr = p >> 4, pc = p & 15;
    float s = 0.f;
    for (int e = threadIdx.x; e < CH * KS * KS; e += 256) {
        int c = e / (KS * KS); int rem = e % (KS * KS);
        int i = rem / KS, j = rem % KS;
        s += x[(c * XH + pr * KS + i) * XW + pc * KS + j];
    }
    __shared__ float red[256];
    red[threadIdx.x] = s; __syncthreads();
    for (int st = 128; st > 0; st >>= 1) {
        if (threadIdx.x < st) red[threadIdx.x] += red[threadIdx.x + st];
        __syncthreads();
    }
    if (threadIdx.x == 0) mx[p] = red[0] * (1.0f / 1728.0f);
}

// fp8 patch matrix, K-REORDERED j-octet-major: plane o' = (j/8)*72 + c*24 + i.
// Sum over k is order-independent, and this makes the A-side LDS-band address affine.
// (R2-proven layout: staging DMA + 4x ds_read_b64 measured ~0 bank conflicts.)
__global__ void k_bmat8(const float* __restrict__ x, uchar_t* __restrict__ bmk) {
    int p = blockIdx.x; int pr = p >> 4, pc = p & 15;
    for (int e = threadIdx.x; e < CH * KS * KS; e += 256) {
        int c = e / (KS * KS), rem = e % (KS * KS), i = rem / KS, j = rem % KS;
        bmk[((j >> 3) * 72 + c * 24 + i) * (NP * 8) + p * 8 + (j & 7)] =
            f2e4m3(x[(c * XH + pr * KS + i) * XW + pc * KS + j]);
    }
}

// 4 column-shifted fp8 copies: y4[S][c][r][t] = fp8(ydec[c][r][t+S]), S in 0..3, 0-pad OOB.
__global__ void k_y4(const float* __restrict__ yd, uchar_t* __restrict__ y4) {
    int idx = blockIdx.x * 256 + threadIdx.x;
    if (idx >= 4 * 3 * HH * (WW / 4)) return;
    int q = idx % (WW / 4); int rem = idx / (WW / 4);
    int r = rem % HH; rem /= HH;
    int c = rem % 3; int S = rem / 3;
    const float* src = yd + (c * HH + r) * WW;
    union { uchar_t u[4]; unsigned v; } o;
    #pragma unroll
    for (int qq = 0; qq < 4; qq++) {
        int t = q * 4 + qq + S;
        o.u[qq] = f2e4m3(t < WW ? src[t] : 0.f);
    }
    ((unsigned*)(y4 + ((size_t)(S * 3 + c) * HH + r) * WW))[q] = o.v;
}

// -------------------- main MFMA correlation kernel (MX-fp8 K=64, pipelined) --------------------
// R4 post-mortem: latency-bound, not throughput-bound (every pipe <35% busy; 2 waves/SIMD,
// register-limited at acc=128+108). This version:
//  * wave tile 128 pos x 32 pat (4 mt): acc = 64 regs -> 3 waves/SIMD (__launch_bounds__(256,3)).
//  * SOFTWARE PIPELINE: per body, read slice s+1 into the NEXT named register set while the
//    MFMAs consume slice s from the CURRENT set -> ds latency hides under the MFMA phase,
//    DMA wait has a full step of slack. lgkmcnt(0) guards buffer overwrite by stage(s+2).
//  * A: 4 shift copies (R2-proven conflict-free b32 pairs: word = 1192*sh + a + 14h covers
//    all 32 banks exactly once per half-wave). B: R2-proven 4x b64. LDS = 35456 B.
//  * ZERO barriers in the K-loop; per-wave s_waitcnt vmcnt(2) only (never drained mid-loop).

#define KBODY(S, ADc, BFc, ADn, BFn)                                          \
  do {                                                                        \
    asm volatile("s_waitcnt lgkmcnt(0)" ::: "memory");                        \
    if ((S) + 2 < NSTEP) {                                                    \
      stageB((S) + 2, (S) & 1);                                               \
      asm volatile("s_waitcnt vmcnt(2)" ::: "memory");                        \
    } else {                                                                  \
      asm volatile("s_waitcnt vmcnt(0)" ::: "memory");                        \
    }                                                                         \
    {                                                                         \
      const uchar_t* Ap = Abase0 + U;                                         \
      _Pragma("unroll")                                                       \
      for (int r = 0; r < 7; r++) {                                           \
        ADn[r].x = *(const int*)(Ap + r * 56);                                \
        ADn[r].y = *(const int*)(Ap + r * 56 + 4);                            \
      }                                                                       \
      const uchar_t* Bp = bwave + (((S) + 1) & 1) * 8192 + h * 1024 + l31 * 8;\
      _Pragma("unroll")                                                       \
      for (int q = 0; q < 4; q++) {                                           \
        v2i t = *(const v2i*)(Bp + q * 256);                                  \
        BFn[2 * q] = t.x; BFn[2 * q + 1] = t.y;                               \
      }                                                                       \
      if (++j3 < 3) U += 448;                                                 \
      else { j3 = 0; if (++c3 < 3) U += 672; else { c3 = 0; U -= 4024; } }    \
    }                                                                         \
    _Pragma("unroll")                                                         \
    for (int mt = 0; mt < 4; mt++) {                                          \
      v8i af8;                                                                \
      _Pragma("unroll")                                                       \
      for (int q = 0; q < 4; q++) {                                           \
        af8[2 * q] = ADc[mt + q].x; af8[2 * q + 1] = ADc[mt + q].y;           \
      }                                                                       \
      acc[mt] = __builtin_amdgcn_mfma_scale_f32_32x32x64_f8f6f4(              \
          af8, BFc, acc[mt], 0, 0, 0, 0x7F7F7F7F, 0, 0x7F7F7F7F);             \
    }                                                                         \
  } while (0)

__global__ __launch_bounds__(256, 3) void k_corr(
    const uchar_t* __restrict__ y4, const uchar_t* __restrict__ bmk,
    const ushort_t* __restrict__ s1m, const ushort_t* __restrict__ ivm,
    const float* __restrict__ mx, ushort_t* __restrict__ ps16)
{
    // ---- XCD-band mapping (heuristic blk%8 -> XCD; wrong mapping only costs speed) ----
    const int xcd = blockIdx.x & 7;
    const int idx = blockIdx.x >> 3;
    const int bstart = (NBY * xcd) >> 3;
    const int bcnt = ((NBY * (xcd + 1)) >> 3) - bstart;
    const int local_by = idx / 48;
    if (local_by >= bcnt) return;                    // idle filler block
    const int rem = idx - local_by * 48;
    const int z = rem / 24;                          // patch half
    const int bx = rem - z * 24;
    const int by = bstart + local_by;

    __shared__ __align__(16) uchar_t Aband[19072];   // 4 copies x 84 rows x 56 B (stride 4768)
    __shared__ __align__(16) uchar_t Bb[16384];      // 2 buf x 4 waves x [8 planes][32 pat][8B]

    const int tid = threadIdx.x;
    const int wave = tid >> 6, lane = tid & 63;
    const int r0 = by * BROWS, w0 = bx * BCOLS;
    const int zbase = z * 128;
    const int l31 = lane & 31, h = lane >> 5;
    const int wn = wave;                             // patch group (wave-exclusive)

    // ---- prologue: load A band (rows r0..r0+27, cols w0..w0+55) from the 4 shifted planes ----
    for (int e = tid; e < 4704; e += 256) {          // 4 copies x 84 rows x 14 dwords
        int dw = e % 14;
        int row84 = (e / 14) % 84;
        int S = e / 1176;
        int c = row84 / 28, r = row84 - c * 28;
        int gr = r0 + r; gr = gr < HH ? gr : HH - 1; // clamp feeds only masked-invalid positions
        unsigned v = *(const unsigned*)(y4 + ((size_t)(S * 3 + c) * HH + gr) * WW + w0 + dw * 4);
        *(unsigned*)(Aband + S * 4768 + row84 * 56 + dw * 4) = v;
    }

    // ---- B staging (wave-private): 8 planes x 32 pat x 8B per slice = 2 KB, 2 DMAs ----
    // lane l covers plane (l>>4), patch-pair (l&15): LDS [4 planes][32 pat][8B] per KB.
    const uchar_t* gB = bmk + (size_t)(lane >> 4) * 2048
                      + (size_t)(zbase + wn * 32) * 8 + (lane & 15) * 16;
    uchar_t* bwave = Bb + wave * 2048;
    auto stageB = [&](int s, int buf) {
        uchar_t* bd = bwave + buf * 8192;
        const uchar_t* g = gB + (size_t)s * 16384;
        gload16(g,        bd);                       // planes 0..3 of slice
        gload16(g + 8192, bd + 1024);                // planes 4..7
    };

    // A frag lane base: addr = sh*4768 + (c*28 + ibase + 4h + q + mt)*56 + (l31 + 8jo - sh)
    //                 = [sh*4767 + l31 + h*224] + U(s) + (mt+q)*56,  sh = l31&3
    const uchar_t* Abase0 = Aband + (l31 & 3) * 4767 + l31 + h * 224;

    v16f acc[4];
    #pragma unroll
    for (int a = 0; a < 4; a++)
        #pragma unroll
        for (int r = 0; r < 16; r++) acc[a][r] = 0.f;

    __syncthreads();                                 // band visible to all waves (one-time)

    stageB(0, 0);
    stageB(1, 1);                                    // 4 DMAs in flight
    asm volatile("s_waitcnt vmcnt(2)" ::: "memory"); // slice 0 landed

    v2i adA[7], adB[7];
    v8i bf8A, bf8B;
    {   // read slice 0 -> A set (U = 0, buf 0)
        const uchar_t* Ap = Abase0;
        #pragma unroll
        for (int r = 0; r < 7; r++) {
            adA[r].x = *(const int*)(Ap + r * 56);
            adA[r].y = *(const int*)(Ap + r * 56 + 4);
        }
        const uchar_t* Bp = bwave + h * 1024 + l31 * 8;
        #pragma unroll
        for (int q = 0; q < 4; q++) {
            v2i t = *(const v2i*)(Bp + q * 256);
            bf8A[2 * q] = t.x; bf8A[2 * q + 1] = t.y;
        }
    }
    int U = 448, j3 = 1, c3 = 0;                     // cursor already advanced to slice 1

    #pragma unroll 1
    for (int p = 0; p < 13; p++) {                   // s = 0..25 (reads 1..26)
        KBODY(2 * p,     adA, bf8A, adB, bf8B);
        KBODY(2 * p + 1, adB, bf8B, adA, bf8A);
    }
    {   // tail s = 26: compute-only on the A set
        #pragma unroll
        for (int mt = 0; mt < 4; mt++) {
            v8i af8;
            #pragma unroll
            for (int q = 0; q < 4; q++) {
                af8[2 * q] = adA[mt + q].x; af8[2 * q + 1] = adA[mt + q].y;
            }
            acc[mt] = __builtin_amdgcn_mfma_scale_f32_32x32x64_f8f6f4(
                af8, bf8A, acc[mt], 0, 0, 0, 0x7F7F7F7F, 0, 0x7F7F7F7F);
        }
    }

    // epilogue: approx score + per-patch max over this block's 128 positions
    float mxp = mx[zbase + wn * 32 + l31];
    float best = -1e30f;
    #pragma unroll
    for (int mt = 0; mt < 4; mt++) {
        int rg = r0 + mt;
        #pragma unroll
        for (int r = 0; r < 16; r++) {
            int row32 = (r & 3) + 8 * (r >> 2) + 4 * h;   // 32x32 C/D row (m74/m101)
            int wg = w0 + row32;
            bool valid = (rg < HC) && (wg < WC);
            int pos = rg * WC + wg;
            float S1 = valid ? bf2f(s1m[pos]) : 0.f;
            float iv = valid ? bf2f(ivm[pos]) : 0.f;
            float sc = valid ? (acc[mt][r] - mxp * S1) * iv : -1e30f;
            best = fmaxf(best, sc);
        }
    }
    best = fmaxf(best, __shfl_xor(best, 32));        // reduce over h
    if (h == 0)
        ps16[(by * NBX + bx) * NP + zbase + wn * 32 + l31] = f2bf(best);
}

// -------------------- per-patch top-8 blocks --------------------

__global__ void k_select(const ushort_t* __restrict__ ps16, int* __restrict__ cand) {
    int p = blockIdx.x, tid = threadIdx.x;
    __shared__ float ls[NBLK];
    __shared__ float rs[256];
    __shared__ int   ri[256];
    for (int e = tid; e < NBLK; e += 256) ls[e] = bf2f(ps16[e * NP + p]);
    __syncthreads();
    for (int round = 0; round < NCAND; round++) {
        float bs = -1e38f; int bi = 0;
        for (int e = tid; e < NBLK; e += 256) if (ls[e] > bs) { bs = ls[e]; bi = e; }
        rs[tid] = bs; ri[tid] = bi; __syncthreads();
        for (int st = 128; st > 0; st >>= 1) {
            if (tid < st && rs[tid + st] > rs[tid]) { rs[tid] = rs[tid + st]; ri[tid] = ri[tid + st]; }
            __syncthreads();
        }
        int win = ri[0];
        if (tid == 0) cand[p * NCAND + round] = win;
        if (tid == (win & 255)) ls[win] = -1e38f;
        __syncthreads();
    }
}

// -------------------- exact fp32 rescore (recomputes window sums) + gather --------------------

__global__ void k_rescore(const int* __restrict__ cand, const float* __restrict__ xdec,
                          const float* __restrict__ ydec, const float* __restrict__ mx,
                          const float* __restrict__ yfull, float* __restrict__ out) {
    int p = blockIdx.x, tid = threadIdx.x;
    int pr = p >> 4, pc = p & 15;
    float mxp = mx[p];
    float best = -1e30f; int bpos = 0x7FFFFFFF;
    #pragma unroll 1
    for (int cdp = 0; cdp < 4; cdp++) {
        int cd = cdp * 2 + (tid >> 7);
        int blk = cand[p * NCAND + cd];
        int r0 = (blk / NBX) * BROWS, w0 = (blk % NBX) * BCOLS;
        int pi = tid & 127;
        int rg = r0 + (pi >> 5), wg = w0 + (pi & 31);
        if (rg < HC && wg < WC) {
            float sxy = 0.f, sy = 0.f, sy2 = 0.f;
            for (int c = 0; c < CH; c++) {
                #pragma unroll 1
                for (int i = 0; i < KS; i++) {
                    const float* yr = ydec + (c * HH + rg + i) * WW + wg;
                    const float* xr = xdec + (c * XH + pr * KS + i) * XW + pc * KS;
                    #pragma unroll
                    for (int j = 0; j < KS; j++) {
                        float yv = yr[j];
                        sxy = fmaf(yv, xr[j], sxy);
                        sy += yv;
                        sy2 = fmaf(yv, yv, sy2);
                    }
                }
            }
            float d2 = sy2 - sy * sy * (1.0f / 576.0f);
            int pos = rg * WC + wg;
            float sc = (sxy - mxp * sy) * rsqrtf(fmaxf(d2, 1e-20f));
            if (sc > best || (sc == best && pos < bpos)) { best = sc; bpos = pos; }
        }
    }
    __shared__ float rs[256];
    __shared__ int   ri[256];
    rs[tid] = best; ri[tid] = bpos; __syncthreads();
    for (int st = 128; st > 0; st >>= 1) {
        if (tid < st) {
            if (rs[tid + st] > rs[tid] || (rs[tid + st] == rs[tid] && ri[tid + st] < ri[tid])) {
                rs[tid] = rs[tid + st]; ri[tid] = ri[tid + st];
            }
        }
        __syncthreads();
    }
    int bestpos = ri[0];
    int row = bestpos / WC, col = bestpos % WC;
    for (int e = tid; e < CH * KS * KS; e += 256) {
        int c = e / (KS * KS), rem = e % (KS * KS), i = rem / KS, j = rem % KS;
        out[p * CH * KS * KS + e] = yfull[(c * HH + row + i) * WW + col + j];
    }
}

// -------------------- launch --------------------
// ws footprint: writes end < 12.1 MB (y4 ends at 12,047,488 B; + tiny transient OOB reads)
// — safely under the >=13.7 MB proven previously.

extern "C" void kernel_launch(void* const* d_in, const int* in_sizes, int n_in,
                              void* d_out, int out_size, void* d_ws, size_t ws_size,
                              hipStream_t stream) {
    const float* xdec = (const float*)d_in[0];   // (1,3,384,384)
    const float* ydec = (const float*)d_in[1];   // (1,3,768,768)
    const float* y    = (const float*)d_in[2];   // (1,3,768,768)
    float* out = (float*)d_out;                  // (256,3,24,24)

    float* ws = (float*)d_ws;
    ushort_t* s1m16 = (ushort_t*)(ws + 0);         // 555025 u16
    ushort_t* ivm16 = (ushort_t*)(ws + 277520);    // 555025 u16
    float*    mx    = ws + 555040;                 // 256
    uchar_t*  Bmk   = (uchar_t*)(ws + 555296);     // 442368 B, k-major reordered (16B-aligned)
    int*      cand  = (int*)(ws + 665888);         // 2048
    ushort_t* ps16  = (ushort_t*)(ws + 667936);    // 1,148,928 u16 [blk][pat]
    uchar_t*  y4    = (uchar_t*)(ws + 1242400);    // 7,077,888 B (16B-aligned)
    // box-sum temps alias ps16+y4 region (dead before k_y4/k_corr):
    float* ksum  = ws + 667936;                    // 589824
    float* ksum2 = ws + 1257760;                   // 589824
    float* h1    = ws + 1847584;                   // 572160
    float* h2    = ws + 2419744;                   // 572160 (end 2,991,904 < 3,011,872)

    k_colsum<<<(HH * WW + 255) / 256, 256, 0, stream>>>(ydec, ksum, ksum2);
    k_hsum<<<(HH * WC + 255) / 256, 256, 0, stream>>>(ksum, ksum2, h1, h2);
    k_vsum<<<(HC * WC + 255) / 256, 256, 0, stream>>>(h1, h2, s1m16, ivm16);
    k_meanx<<<NP, 256, 0, stream>>>(xdec, mx);
    k_bmat8<<<NP, 256, 0, stream>>>(xdec, Bmk);
    k_y4<<<(4 * 3 * HH * (WW / 4) + 255) / 256, 256, 0, stream>>>(ydec, y4);

    k_corr<<<NGRID, 256, 0, stream>>>(y4, Bmk, s1m16, ivm16, mx, ps16);
    k_select<<<NP, 256, 0, stream>>>(ps16, cand);
    k_rescore<<<NP, 256, 0, stream>>>(cand, xdec, ydec, mx, y, out);
}